// Round 7
// baseline (114.375 us; speedup 1.0000x reference)
//
#include <hip/hip_runtime.h>

#define NPTS  8192
#define BATCH 4

typedef short  bf8   __attribute__((ext_vector_type(8)));   // 8 bf16 = 4 VGPRs
typedef float  f32x4 __attribute__((ext_vector_type(4)));
typedef float  v2f   __attribute__((ext_vector_type(2)));

__device__ inline unsigned short bf16_rne(float x) {
    unsigned u = __float_as_uint(x);
    unsigned r = (u + 0x7FFFu + ((u >> 16) & 1u)) >> 16;   // round-nearest-even
    return (unsigned short)r;
}
__device__ inline float bf16_to_f(unsigned short h) {
    return __uint_as_float(((unsigned)h) << 16);
}
// Order-preserving float<->uint encode so atomicMax(uint) == float max.
__device__ inline unsigned fenc(float x) {
    unsigned b = __float_as_uint(x);
    return (b & 0x80000000u) ? ~b : (b | 0x80000000u);
}
__device__ inline float fdec(unsigned k) {
    unsigned b = (k & 0x80000000u) ? (k ^ 0x80000000u) : ~k;
    return __uint_as_float(b);
}

// ============================================================================
// MFMA path (fragment layouts + K-dup trick VERIFIED: R5/R6 absmax 0.0).
// ||s-d||^2 = -2*(s.d + w_s + w_d), w_p = -0.5*||p||^2.
// K-slots 0..15: A=[xh yh zh xl yl zl xh yh | zh 1 1 wh wl 0 0 0]
//               B=[xh yh zh xh yh zh xl yl | zl wh wl 1 1 0 0 0]
// K 16..31 duplicate 0..15 (lane&31 indexing) => C = 2*(s.d+w_s+w_d),
// dist = max(-C, 0). Per-n min over m == row-max of C.
// R7: B-fragments staged in LDS (32 KB/block); per-n max merged globally via
// atomicMax on order-encoded uints (max is commutative -> deterministic).
// ============================================================================

__global__ void pack_mfma(const float* __restrict__ f, const float* __restrict__ f_,
                          bf8* __restrict__ fA, bf8* __restrict__ fB,
                          bf8* __restrict__ gA, bf8* __restrict__ gB,
                          unsigned* __restrict__ seg, float* __restrict__ out) {
    int j = blockIdx.x * blockDim.x + threadIdx.x;   // 0..65535
    if (j == 0) out[0] = 0.0f;                       // d_out poisoned 0xAA
    seg[j] = 0u;                                     // < fenc of any real value
    int cloud = j >> 15;
    int idx   = j & 32767;                           // b*8192 + p
    const float* src = cloud ? f_ : f;
    float x = src[idx * 3 + 0], y = src[idx * 3 + 1], z = src[idx * 3 + 2];
    float w = -0.5f * (x * x + y * y + z * z);
    unsigned short xh = bf16_rne(x), yh = bf16_rne(y), zh = bf16_rne(z);
    unsigned short xl = bf16_rne(x - bf16_to_f(xh));
    unsigned short yl = bf16_rne(y - bf16_to_f(yh));
    unsigned short zl = bf16_rne(z - bf16_to_f(zh));
    unsigned short wh = bf16_rne(w);
    unsigned short wl = bf16_rne(w - bf16_to_f(wh));
    const short ONE = (short)0x3F80;                 // bf16 1.0

    bf8 A0, A1, B0, B1;
    A0[0]=(short)xh; A0[1]=(short)yh; A0[2]=(short)zh; A0[3]=(short)xl;
    A0[4]=(short)yl; A0[5]=(short)zl; A0[6]=(short)xh; A0[7]=(short)yh;
    A1[0]=(short)zh; A1[1]=ONE;       A1[2]=ONE;       A1[3]=(short)wh;
    A1[4]=(short)wl; A1[5]=0;         A1[6]=0;         A1[7]=0;
    B0[0]=(short)xh; B0[1]=(short)yh; B0[2]=(short)zh; B0[3]=(short)xh;
    B0[4]=(short)yh; B0[5]=(short)zh; B0[6]=(short)xl; B0[7]=(short)yl;
    B1[0]=(short)zl; B1[1]=(short)wh; B1[2]=(short)wl; B1[3]=ONE;
    B1[4]=ONE;       B1[5]=0;         B1[6]=0;         B1[7]=0;

    int b = idx >> 13, p = idx & 8191;
    int t = p >> 4, li = p & 15;
    size_t slot = ((size_t)(b * 512 + t)) * 32;
    bf8* Adst = cloud ? gA : fA;
    bf8* Bdst = cloud ? gB : fB;
    Adst[slot + li]      = A0;
    Adst[slot + 16 + li] = A1;
    Bdst[slot + li]      = B0;
    Bdst[slot + 16 + li] = B1;
}

// 2048 blocks x 256 thr (4 waves). Block = (pass, b, nblk: 32 tiles = 512 rows,
// mseg: 1024 m = 64 tiles). Waves partition n (8 tiles each), share the LDS
// B-stage; no cross-wave reduce. Per pair-iter: 2 ds_read_b128, 16 MFMA,
// 32 v_max3. Epilogue: 16-lane butterfly row-max -> atomicMax(enc) into seg.
__global__ __launch_bounds__(256, 4) void chamfer_mfma(
        const bf8* __restrict__ fA, const bf8* __restrict__ fB,
        const bf8* __restrict__ gA, const bf8* __restrict__ gB,
        unsigned* __restrict__ seg) {
    __shared__ bf8 lbs[2048];                       // 64 B-tiles = 32 KB

    int tid  = threadIdx.x;
    int wv   = tid >> 6, lane = tid & 63, li = lane & 31;
    int bx   = blockIdx.x;
    int mseg = bx & 7;
    int nblk = (bx >> 3) & 15;
    int b    = (bx >> 7) & 3;
    int pass = bx >> 9;

    const bf8* __restrict__ Af = pass ? gA : fA;    // rows (query side)
    const bf8* __restrict__ Bf = pass ? fB : gB;    // cols (target side)

    // Stage this block's 64 B-tiles into LDS (each thread copies 8x 16B).
    const bf8* __restrict__ bp = Bf + ((size_t)(b * 512 + mseg * 64)) * 32;
#pragma unroll
    for (int k = 0; k < 8; ++k) lbs[k * 256 + tid] = bp[k * 256 + tid];

    // This wave's 8 n-tiles (128 rows).
    bf8 a[8];
    f32x4 rmax[8];
    int nt_base = b * 512 + nblk * 32 + wv * 8;
#pragma unroll
    for (int s = 0; s < 8; ++s) {
        a[s] = Af[(size_t)(nt_base + s) * 32 + li];
        rmax[s] = (f32x4)(-3.0e38f);
    }
    __syncthreads();

    f32x4 zc = (f32x4)(0.0f);
#pragma unroll 2
    for (int i = 0; i < 32; ++i) {                  // 32 pair-iters = 64 tiles
        bf8 qa = lbs[i * 64 + li];
        bf8 qb = lbs[i * 64 + 32 + li];
#pragma unroll
        for (int s = 0; s < 8; ++s) {
            f32x4 d0 = __builtin_amdgcn_mfma_f32_16x16x32_bf16(a[s], qa, zc, 0, 0, 0);
            f32x4 d1 = __builtin_amdgcn_mfma_f32_16x16x32_bf16(a[s], qb, zc, 0, 0, 0);
            rmax[s] = __builtin_elementwise_max(
                          __builtin_elementwise_max(rmax[s], d0), d1);  // v_max3
        }
    }

    // Row-max across 16 cols: butterfly within 16-lane groups.
#pragma unroll
    for (int s = 0; s < 8; ++s) {
#pragma unroll
        for (int m = 1; m < 16; m <<= 1) {
            f32x4 o;
            o[0] = __shfl_xor(rmax[s][0], m, 64);
            o[1] = __shfl_xor(rmax[s][1], m, 64);
            o[2] = __shfl_xor(rmax[s][2], m, 64);
            o[3] = __shfl_xor(rmax[s][3], m, 64);
            rmax[s] = __builtin_elementwise_max(rmax[s], o);
        }
    }

    // C/D row = (lane>>4)*4 + reg; lanes 0,16,32,48 hold 4 rows per s-tile.
    if ((lane & 15) == 0) {
        int quad = lane >> 4;
        unsigned* sg = seg + (size_t)(pass * 4 + b) * NPTS + nblk * 512 + wv * 128;
#pragma unroll
        for (int s = 0; s < 8; ++s)
#pragma unroll
            for (int r = 0; r < 4; ++r)
                atomicMax(&sg[s * 16 + quad * 4 + r], fenc(rmax[s][r]));
    }
}

__global__ __launch_bounds__(1024) void finalize_mfma(
        const unsigned* __restrict__ seg, float* __restrict__ out) {
    __shared__ float partial[16];
    int j = blockIdx.x * 1024 + threadIdx.x;        // (pass*4+b)*8192 + n
    float emax = fdec(seg[j]);
    float dist = fmaxf(-emax, 0.0f);                // C held 2x payload
    for (int off = 32; off > 0; off >>= 1)
        dist += __shfl_down(dist, off, 64);
    int lane = threadIdx.x & 63, wv = threadIdx.x >> 6;
    if (lane == 0) partial[wv] = dist;
    __syncthreads();
    if (threadIdx.x < 16) {
        float s = partial[threadIdx.x];
        for (int off = 8; off > 0; off >>= 1)
            s += __shfl_down(s, off, 64);
        if (threadIdx.x == 0) atomicAdd(out, s * (1.0f / 32768.0f));
    }
}

// ============================================================================
// Fallback 1 (ws >= 3MB): verified R4 packed-fp32 path (45.7 us main).
// ============================================================================

__global__ void pack_pk(const float* __restrict__ f, const float* __restrict__ f_,
                        float4* __restrict__ pk, float* __restrict__ prf,
                        float* __restrict__ out) {
    int j = blockIdx.x * blockDim.x + threadIdx.x;
    if (j == 0) out[0] = 0.0f;
    const float* src = (j >= 32768) ? f_ : f;
    int idx = j & 32767;
    float x = src[idx * 3 + 0], y = src[idx * 3 + 1], z = src[idx * 3 + 2];
    float w = -0.5f * (x * x + y * y + z * z);
    pk[j] = make_float4(x, y, z, w);
    int  slot = j & 1;
    long base = (long)(j >> 1) * 8;
    prf[base + 0 + slot] = x;
    prf[base + 2 + slot] = y;
    prf[base + 4 + slot] = z;
    prf[base + 6 + slot] = w;
}

__global__ __launch_bounds__(512, 8) void chamfer_pk(
        const float4* __restrict__ pk, const float4* __restrict__ pr,
        float* __restrict__ seg) {
    __shared__ float red[8][256];
    int tid  = threadIdx.x;
    int wv   = __builtin_amdgcn_readfirstlane(tid >> 6);
    int lane = tid & 63;
    int bx   = blockIdx.x;
    int tile = bx & 31;
    int b    = (bx >> 5) & 3;
    int dir  = (bx >> 7) & 1;
    int mq   = bx >> 8;

    const float4* __restrict__ A = pk + ((size_t)dir * BATCH + b) * NPTS;
    int n_base = tile * 256;
    v2f px[4], py[4], pz[4], e2[4];
#pragma unroll
    for (int r = 0; r < 4; ++r) {
        float4 p = A[n_base + lane + 64 * r];
        px[r] = (v2f){p.x, p.x};
        py[r] = (v2f){p.y, p.y};
        pz[r] = (v2f){p.z, p.z};
        e2[r] = (v2f){-1e30f, -1e30f};
    }
    int sb_m = (1 - dir) * BATCH + b;
    const float4* __restrict__ mp =
        pr + ((size_t)sb_m * 4096 + mq * 1024 + wv * 128) * 2;

    for (int i = 0; i < 128; i += 4) {
#pragma unroll
        for (int u = 0; u < 4; ++u) {
            float4 qa = mp[(i + u) * 2 + 0];
            float4 qb = mp[(i + u) * 2 + 1];
            v2f qx = (v2f){qa.x, qa.y};
            v2f qy = (v2f){qa.z, qa.w};
            v2f qz = (v2f){qb.x, qb.y};
            v2f qw = (v2f){qb.z, qb.w};
#pragma unroll
            for (int r = 0; r < 4; ++r) {
                v2f c = __builtin_elementwise_fma(px[r], qx, qw);
                c = __builtin_elementwise_fma(py[r], qy, c);
                c = __builtin_elementwise_fma(pz[r], qz, c);
                e2[r] = __builtin_elementwise_max(e2[r], c);
            }
        }
    }
#pragma unroll
    for (int r = 0; r < 4; ++r)
        red[wv][lane + 64 * r] = fmaxf(e2[r].x, e2[r].y);
    __syncthreads();
    if (tid < 256) {
        float emax = red[0][tid];
#pragma unroll
        for (int ww = 1; ww < 8; ++ww) emax = fmaxf(emax, red[ww][tid]);
        seg[mq * (2 * BATCH * NPTS) + dir * (BATCH * NPTS) + b * NPTS
            + n_base + tid] = emax;
    }
}

__global__ __launch_bounds__(1024) void finalize_pk(
        const float4* __restrict__ pk, const float* __restrict__ seg,
        float* __restrict__ out) {
    __shared__ float partial[16];
    int j = blockIdx.x * 1024 + threadIdx.x;
    float emax = seg[j];
#pragma unroll
    for (int q = 1; q < 4; ++q) emax = fmaxf(emax, seg[q * 65536 + j]);
    float dist = fmaxf(-2.0f * (emax + pk[j].w), 0.0f);
    for (int off = 32; off > 0; off >>= 1)
        dist += __shfl_down(dist, off, 64);
    int lane = threadIdx.x & 63, wv = threadIdx.x >> 6;
    if (lane == 0) partial[wv] = dist;
    __syncthreads();
    if (threadIdx.x < 16) {
        float s = partial[threadIdx.x];
        for (int off = 8; off > 0; off >>= 1)
            s += __shfl_down(s, off, 64);
        if (threadIdx.x == 0) atomicAdd(out, s * (1.0f / 32768.0f));
    }
}

// ============================================================================
// Fallback 2 (no ws): verified R2 kernel.
// ============================================================================

__global__ void zero_out_kernel(float* __restrict__ out) { out[0] = 0.0f; }

__global__ __launch_bounds__(1024) void chamfer_fallback(
        const float* __restrict__ f, const float* __restrict__ f_,
        float* __restrict__ out) {
    __shared__ float wlds[NPTS];
    __shared__ float red[16][256];
    __shared__ float partial[4];
    int tid  = threadIdx.x;
    int wv   = __builtin_amdgcn_readfirstlane(tid >> 6);
    int lane = tid & 63;
    int bx   = blockIdx.x;
    int dir  = bx >> 7;
    int b    = (bx >> 5) & 3;
    int tile = bx & 31;
    int n_base = tile * 256;
    const float* __restrict__ A  = dir ? f_ : f;
    const float* __restrict__ Bm = dir ? f  : f_;
    const float* an = A  + (size_t)b * NPTS * 3;
    const float* bm = Bm + (size_t)b * NPTS * 3;
    for (int i = tid; i < NPTS; i += 1024) {
        float x = bm[i * 3 + 0], y = bm[i * 3 + 1], z = bm[i * 3 + 2];
        wlds[i] = -0.5f * (x * x + y * y + z * z);
    }
    float xn[4], yn[4], zn[4];
#pragma unroll
    for (int r = 0; r < 4; ++r) {
        int n = n_base + lane + 64 * r;
        xn[r] = an[n * 3 + 0]; yn[r] = an[n * 3 + 1]; zn[r] = an[n * 3 + 2];
    }
    __syncthreads();
    float e[4];
#pragma unroll
    for (int r = 0; r < 4; ++r) e[r] = -1e30f;
    int m0 = wv * (NPTS / 16);
#pragma unroll 4
    for (int i = 0; i < NPTS / 16; ++i) {
        int m = m0 + i;
        float qx = bm[m * 3 + 0], qy = bm[m * 3 + 1], qz = bm[m * 3 + 2];
        float qw = wlds[m];
#pragma unroll
        for (int r = 0; r < 4; ++r) {
            float c = fmaf(zn[r], qz, fmaf(yn[r], qy, fmaf(xn[r], qx, qw)));
            e[r] = fmaxf(e[r], c);
        }
    }
#pragma unroll
    for (int r = 0; r < 4; ++r) red[wv][lane + 64 * r] = e[r];
    __syncthreads();
    if (tid < 256) {
        float emax = red[0][tid];
#pragma unroll
        for (int ww = 1; ww < 16; ++ww) emax = fmaxf(emax, red[ww][tid]);
        int n = n_base + tid;
        float x = an[n * 3 + 0], y = an[n * 3 + 1], z = an[n * 3 + 2];
        float dist = fmaxf(x * x + y * y + z * z - 2.0f * emax, 0.0f);
        for (int off = 32; off > 0; off >>= 1)
            dist += __shfl_down(dist, off, 64);
        if ((tid & 63) == 0) partial[tid >> 6] = dist;
    }
    __syncthreads();
    if (tid == 0) {
        float s = partial[0] + partial[1] + partial[2] + partial[3];
        atomicAdd(out, s * (1.0f / 32768.0f));
    }
}

extern "C" void kernel_launch(void* const* d_in, const int* in_sizes, int n_in,
                              void* d_out, int out_size, void* d_ws, size_t ws_size,
                              hipStream_t stream) {
    const float* f  = (const float*)d_in[0];
    const float* f_ = (const float*)d_in[1];
    float* out = (float*)d_out;

    const size_t MB = 1048576;
    if (ws_size >= 5 * MB) {
        bf8*      fA  = (bf8*)d_ws;                        // f  as A-role, 1 MB
        bf8*      fB  = (bf8*)((char*)d_ws + 1 * MB);      // f  as B-role
        bf8*      gA  = (bf8*)((char*)d_ws + 2 * MB);      // f_ as A-role
        bf8*      gB  = (bf8*)((char*)d_ws + 3 * MB);      // f_ as B-role
        unsigned* seg = (unsigned*)((char*)d_ws + 4 * MB); // 256 KB
        pack_mfma<<<256, 256, 0, stream>>>(f, f_, fA, fB, gA, gB, seg, out);
        chamfer_mfma<<<2048, 256, 0, stream>>>(fA, fB, gA, gB, seg);
        finalize_mfma<<<64, 1024, 0, stream>>>(seg, out);
    } else if (ws_size >= 3 * MB) {
        float4* pk = (float4*)d_ws;
        float4* pr = (float4*)((char*)d_ws + 1 * MB);
        float*  sg = (float*)((char*)d_ws + 2 * MB);
        pack_pk<<<256, 256, 0, stream>>>(f, f_, pk, (float*)pr, out);
        chamfer_pk<<<1024, 512, 0, stream>>>(pk, pr, sg);
        finalize_pk<<<64, 1024, 0, stream>>>(pk, sg, out);
    } else {
        zero_out_kernel<<<1, 1, 0, stream>>>(out);
        chamfer_fallback<<<256, 1024, 0, stream>>>(f, f_, out);
    }
}

// Round 8
// 109.219 us; speedup vs baseline: 1.0472x; 1.0472x over previous
//
#include <hip/hip_runtime.h>

#define NPTS  8192
#define BATCH 4

typedef short  bf8    __attribute__((ext_vector_type(8)));   // 8 bf16 = 4 VGPRs
typedef float  f32x16 __attribute__((ext_vector_type(16)));
typedef float  v2f    __attribute__((ext_vector_type(2)));

__device__ inline unsigned short bf16_rne(float x) {
    unsigned u = __float_as_uint(x);
    unsigned r = (u + 0x7FFFu + ((u >> 16) & 1u)) >> 16;   // round-nearest-even
    return (unsigned short)r;
}
__device__ inline float bf16_to_f(unsigned short h) {
    return __uint_as_float(((unsigned)h) << 16);
}
// Order-preserving float<->uint encode so atomicMax(uint) == float max.
__device__ inline unsigned fenc(float x) {
    unsigned b = __float_as_uint(x);
    return (b & 0x80000000u) ? ~b : (b | 0x80000000u);
}
__device__ inline float fdec(unsigned k) {
    unsigned b = (k & 0x80000000u) ? (k ^ 0x80000000u) : ~k;
    return __uint_as_float(b);
}

// ============================================================================
// MFMA path, R8: v_mfma_f32_32x32x16_bf16 (K=16 — no K-duplication waste).
// ||s-d||^2 = -2*(s.d + w_s + w_d), w_p = -0.5*||p||^2.
// K-slots (16): A = [xh yh zh xl yl zl xh yh | zh 1 1 wh wl 0 0 0]
//               B = [xh yh zh xh yh zh xl yl | zl wh wl 1 1 0 0 0]
//   => C[n,m] = s.d (split-bf16) + w_s + w_d;  dist = max(-2C, 0).
// Operand layouts: A/B: point = lane&31, k = (lane>>5)*8 + j  (same lane-group
// pattern R5-verified on 16x16x32); C/D (HW-verified m74/m101):
// col = lane&31, row = (reg&3) + 8*(reg>>2) + 4*(lane>>5).
// Frag storage per role: [b][tile32][khalf<2][pt&31] x 16B -> lane-linear.
// ============================================================================

__global__ void pack_mfma(const float* __restrict__ f, const float* __restrict__ f_,
                          bf8* __restrict__ fA, bf8* __restrict__ fB,
                          bf8* __restrict__ gA, bf8* __restrict__ gB,
                          unsigned* __restrict__ seg, float* __restrict__ out) {
    int j = blockIdx.x * blockDim.x + threadIdx.x;   // 0..65535
    if (j == 0) out[0] = 0.0f;                       // d_out poisoned 0xAA
    seg[j] = 0u;                                     // < fenc of any real value
    int cloud = j >> 15;
    int idx   = j & 32767;                           // b*8192 + p
    const float* src = cloud ? f_ : f;
    float x = src[idx * 3 + 0], y = src[idx * 3 + 1], z = src[idx * 3 + 2];
    float w = -0.5f * (x * x + y * y + z * z);
    unsigned short xh = bf16_rne(x), yh = bf16_rne(y), zh = bf16_rne(z);
    unsigned short xl = bf16_rne(x - bf16_to_f(xh));
    unsigned short yl = bf16_rne(y - bf16_to_f(yh));
    unsigned short zl = bf16_rne(z - bf16_to_f(zh));
    unsigned short wh = bf16_rne(w);
    unsigned short wl = bf16_rne(w - bf16_to_f(wh));
    const short ONE = (short)0x3F80;                 // bf16 1.0

    bf8 A0, A1, B0, B1;
    A0[0]=(short)xh; A0[1]=(short)yh; A0[2]=(short)zh; A0[3]=(short)xl;
    A0[4]=(short)yl; A0[5]=(short)zl; A0[6]=(short)xh; A0[7]=(short)yh;
    A1[0]=(short)zh; A1[1]=ONE;       A1[2]=ONE;       A1[3]=(short)wh;
    A1[4]=(short)wl; A1[5]=0;         A1[6]=0;         A1[7]=0;
    B0[0]=(short)xh; B0[1]=(short)yh; B0[2]=(short)zh; B0[3]=(short)xh;
    B0[4]=(short)yh; B0[5]=(short)zh; B0[6]=(short)xl; B0[7]=(short)yl;
    B1[0]=(short)zl; B1[1]=(short)wh; B1[2]=(short)wl; B1[3]=ONE;
    B1[4]=ONE;       B1[5]=0;         B1[6]=0;         B1[7]=0;

    int b = idx >> 13, p = idx & 8191;
    int t = p >> 5, li = p & 31;                     // 32-point tiles now
    size_t base = ((size_t)(b * 256 + t)) * 64;
    bf8* Adst = cloud ? gA : fA;
    bf8* Bdst = cloud ? gB : fB;
    Adst[base + li]      = A0;                       // khalf 0
    Adst[base + 32 + li] = A1;                       // khalf 1
    Bdst[base + li]      = B0;
    Bdst[base + 32 + li] = B1;
}

// 1024 blocks x 256 thr (4 waves). Block = (pass, b, nblk: 512 rows, mseg:
// 1024 m = 32 tiles staged in 32 KB LDS). Wave holds 4 n-tiles (128 rows).
// Per pair-iter: 2 ds_read_b128, 8 MFMA(32x32x16), 64 v_max3.
// Epilogue: 5-step butterfly row-max over 32 cols -> atomicMax(enc) into seg.
__global__ __launch_bounds__(256, 4) void chamfer_mfma(
        const bf8* __restrict__ fA, const bf8* __restrict__ fB,
        const bf8* __restrict__ gA, const bf8* __restrict__ gB,
        unsigned* __restrict__ seg) {
    __shared__ bf8 lbs[2048];                        // 32 m-tiles = 32 KB

    int tid  = threadIdx.x;
    int wv   = tid >> 6, lane = tid & 63;
    int bx   = blockIdx.x;
    int mseg = bx & 7;
    int nblk = (bx >> 3) & 15;
    int b    = (bx >> 7) & 3;
    int pass = bx >> 9;

    const bf8* __restrict__ Af = pass ? gA : fA;     // rows (query side)
    const bf8* __restrict__ Bf = pass ? fB : gB;     // cols (target side)

    // Stage this block's 32 B-tiles (1024 m-points) into LDS: 8x 16B/thread.
    const bf8* __restrict__ bp = Bf + ((size_t)(b * 256 + mseg * 32)) * 64;
#pragma unroll
    for (int k = 0; k < 8; ++k) lbs[k * 256 + tid] = bp[k * 256 + tid];

    // This wave's 4 n-tiles (128 rows).
    bf8 a[4];
    f32x16 rmax[4];
    int nt_loc = nblk * 16 + wv * 4;                 // tile idx within batch
#pragma unroll
    for (int s = 0; s < 4; ++s) {
        a[s] = Af[(size_t)(b * 256 + nt_loc + s) * 64 + lane];
        rmax[s] = (f32x16)(-3.0e38f);
    }
    __syncthreads();

    f32x16 zc = (f32x16)(0.0f);
    for (int i = 0; i < 16; ++i) {                   // 16 pair-iters = 32 tiles
        bf8 qa = lbs[(2 * i) * 64 + lane];
        bf8 qb = lbs[(2 * i + 1) * 64 + lane];
#pragma unroll
        for (int s = 0; s < 4; ++s) {
            f32x16 d0 = __builtin_amdgcn_mfma_f32_32x32x16_bf16(a[s], qa, zc, 0, 0, 0);
            f32x16 d1 = __builtin_amdgcn_mfma_f32_32x32x16_bf16(a[s], qb, zc, 0, 0, 0);
            rmax[s] = __builtin_elementwise_max(
                          __builtin_elementwise_max(rmax[s], d0), d1);  // v_max3
        }
    }

    // Row-max across 32 cols (col = lane&31): 5-step butterfly.
#pragma unroll
    for (int s = 0; s < 4; ++s) {
#pragma unroll
        for (int m = 1; m < 32; m <<= 1) {
            f32x16 o;
#pragma unroll
            for (int r = 0; r < 16; ++r) o[r] = __shfl_xor(rmax[s][r], m, 64);
            rmax[s] = __builtin_elementwise_max(rmax[s], o);
        }
    }

    // C/D row = (reg&3) + 8*(reg>>2) + 4*(lane>>5); lanes 0 and 32 write.
    if ((lane & 31) == 0) {
        int rbase = (lane >> 5) * 4;
        unsigned* sg = seg + (size_t)(pass * 4 + b) * NPTS;
#pragma unroll
        for (int s = 0; s < 4; ++s) {
            int n0 = (nt_loc + s) * 32;
#pragma unroll
            for (int r = 0; r < 16; ++r) {
                int row = (r & 3) + 8 * (r >> 2) + rbase;
                atomicMax(&sg[n0 + row], fenc(rmax[s][r]));
            }
        }
    }
}

__global__ __launch_bounds__(1024) void finalize_mfma(
        const unsigned* __restrict__ seg, float* __restrict__ out) {
    __shared__ float partial[16];
    int j = blockIdx.x * 1024 + threadIdx.x;         // (pass*4+b)*8192 + n
    float emax = fdec(seg[j]);
    float dist = fmaxf(-2.0f * emax, 0.0f);          // C = s.d + w_s + w_d
    for (int off = 32; off > 0; off >>= 1)
        dist += __shfl_down(dist, off, 64);
    int lane = threadIdx.x & 63, wv = threadIdx.x >> 6;
    if (lane == 0) partial[wv] = dist;
    __syncthreads();
    if (threadIdx.x < 16) {
        float s = partial[threadIdx.x];
        for (int off = 8; off > 0; off >>= 1)
            s += __shfl_down(s, off, 64);
        if (threadIdx.x == 0) atomicAdd(out, s * (1.0f / 32768.0f));
    }
}

// ============================================================================
// Fallback 1 (ws >= 3MB): verified R4 packed-fp32 path (45.7 us main).
// ============================================================================

__global__ void pack_pk(const float* __restrict__ f, const float* __restrict__ f_,
                        float4* __restrict__ pk, float* __restrict__ prf,
                        float* __restrict__ out) {
    int j = blockIdx.x * blockDim.x + threadIdx.x;
    if (j == 0) out[0] = 0.0f;
    const float* src = (j >= 32768) ? f_ : f;
    int idx = j & 32767;
    float x = src[idx * 3 + 0], y = src[idx * 3 + 1], z = src[idx * 3 + 2];
    float w = -0.5f * (x * x + y * y + z * z);
    pk[j] = make_float4(x, y, z, w);
    int  slot = j & 1;
    long base = (long)(j >> 1) * 8;
    prf[base + 0 + slot] = x;
    prf[base + 2 + slot] = y;
    prf[base + 4 + slot] = z;
    prf[base + 6 + slot] = w;
}

__global__ __launch_bounds__(512, 8) void chamfer_pk(
        const float4* __restrict__ pk, const float4* __restrict__ pr,
        float* __restrict__ seg) {
    __shared__ float red[8][256];
    int tid  = threadIdx.x;
    int wv   = __builtin_amdgcn_readfirstlane(tid >> 6);
    int lane = tid & 63;
    int bx   = blockIdx.x;
    int tile = bx & 31;
    int b    = (bx >> 5) & 3;
    int dir  = (bx >> 7) & 1;
    int mq   = bx >> 8;

    const float4* __restrict__ A = pk + ((size_t)dir * BATCH + b) * NPTS;
    int n_base = tile * 256;
    v2f px[4], py[4], pz[4], e2[4];
#pragma unroll
    for (int r = 0; r < 4; ++r) {
        float4 p = A[n_base + lane + 64 * r];
        px[r] = (v2f){p.x, p.x};
        py[r] = (v2f){p.y, p.y};
        pz[r] = (v2f){p.z, p.z};
        e2[r] = (v2f){-1e30f, -1e30f};
    }
    int sb_m = (1 - dir) * BATCH + b;
    const float4* __restrict__ mp =
        pr + ((size_t)sb_m * 4096 + mq * 1024 + wv * 128) * 2;

    for (int i = 0; i < 128; i += 4) {
#pragma unroll
        for (int u = 0; u < 4; ++u) {
            float4 qa = mp[(i + u) * 2 + 0];
            float4 qb = mp[(i + u) * 2 + 1];
            v2f qx = (v2f){qa.x, qa.y};
            v2f qy = (v2f){qa.z, qa.w};
            v2f qz = (v2f){qb.x, qb.y};
            v2f qw = (v2f){qb.z, qb.w};
#pragma unroll
            for (int r = 0; r < 4; ++r) {
                v2f c = __builtin_elementwise_fma(px[r], qx, qw);
                c = __builtin_elementwise_fma(py[r], qy, c);
                c = __builtin_elementwise_fma(pz[r], qz, c);
                e2[r] = __builtin_elementwise_max(e2[r], c);
            }
        }
    }
#pragma unroll
    for (int r = 0; r < 4; ++r)
        red[wv][lane + 64 * r] = fmaxf(e2[r].x, e2[r].y);
    __syncthreads();
    if (tid < 256) {
        float emax = red[0][tid];
#pragma unroll
        for (int ww = 1; ww < 8; ++ww) emax = fmaxf(emax, red[ww][tid]);
        seg[mq * (2 * BATCH * NPTS) + dir * (BATCH * NPTS) + b * NPTS
            + n_base + tid] = emax;
    }
}

__global__ __launch_bounds__(1024) void finalize_pk(
        const float4* __restrict__ pk, const float* __restrict__ seg,
        float* __restrict__ out) {
    __shared__ float partial[16];
    int j = blockIdx.x * 1024 + threadIdx.x;
    float emax = seg[j];
#pragma unroll
    for (int q = 1; q < 4; ++q) emax = fmaxf(emax, seg[q * 65536 + j]);
    float dist = fmaxf(-2.0f * (emax + pk[j].w), 0.0f);
    for (int off = 32; off > 0; off >>= 1)
        dist += __shfl_down(dist, off, 64);
    int lane = threadIdx.x & 63, wv = threadIdx.x >> 6;
    if (lane == 0) partial[wv] = dist;
    __syncthreads();
    if (threadIdx.x < 16) {
        float s = partial[threadIdx.x];
        for (int off = 8; off > 0; off >>= 1)
            s += __shfl_down(s, off, 64);
        if (threadIdx.x == 0) atomicAdd(out, s * (1.0f / 32768.0f));
    }
}

// ============================================================================
// Fallback 2 (no ws): verified R2 kernel.
// ============================================================================

__global__ void zero_out_kernel(float* __restrict__ out) { out[0] = 0.0f; }

__global__ __launch_bounds__(1024) void chamfer_fallback(
        const float* __restrict__ f, const float* __restrict__ f_,
        float* __restrict__ out) {
    __shared__ float wlds[NPTS];
    __shared__ float red[16][256];
    __shared__ float partial[4];
    int tid  = threadIdx.x;
    int wv   = __builtin_amdgcn_readfirstlane(tid >> 6);
    int lane = tid & 63;
    int bx   = blockIdx.x;
    int dir  = bx >> 7;
    int b    = (bx >> 5) & 3;
    int tile = bx & 31;
    int n_base = tile * 256;
    const float* __restrict__ A  = dir ? f_ : f;
    const float* __restrict__ Bm = dir ? f  : f_;
    const float* an = A  + (size_t)b * NPTS * 3;
    const float* bm = Bm + (size_t)b * NPTS * 3;
    for (int i = tid; i < NPTS; i += 1024) {
        float x = bm[i * 3 + 0], y = bm[i * 3 + 1], z = bm[i * 3 + 2];
        wlds[i] = -0.5f * (x * x + y * y + z * z);
    }
    float xn[4], yn[4], zn[4];
#pragma unroll
    for (int r = 0; r < 4; ++r) {
        int n = n_base + lane + 64 * r;
        xn[r] = an[n * 3 + 0]; yn[r] = an[n * 3 + 1]; zn[r] = an[n * 3 + 2];
    }
    __syncthreads();
    float e[4];
#pragma unroll
    for (int r = 0; r < 4; ++r) e[r] = -1e30f;
    int m0 = wv * (NPTS / 16);
#pragma unroll 4
    for (int i = 0; i < NPTS / 16; ++i) {
        int m = m0 + i;
        float qx = bm[m * 3 + 0], qy = bm[m * 3 + 1], qz = bm[m * 3 + 2];
        float qw = wlds[m];
#pragma unroll
        for (int r = 0; r < 4; ++r) {
            float c = fmaf(zn[r], qz, fmaf(yn[r], qy, fmaf(xn[r], qx, qw)));
            e[r] = fmaxf(e[r], c);
        }
    }
#pragma unroll
    for (int r = 0; r < 4; ++r) red[wv][lane + 64 * r] = e[r];
    __syncthreads();
    if (tid < 256) {
        float emax = red[0][tid];
#pragma unroll
        for (int ww = 1; ww < 16; ++ww) emax = fmaxf(emax, red[ww][tid]);
        int n = n_base + tid;
        float x = an[n * 3 + 0], y = an[n * 3 + 1], z = an[n * 3 + 2];
        float dist = fmaxf(x * x + y * y + z * z - 2.0f * emax, 0.0f);
        for (int off = 32; off > 0; off >>= 1)
            dist += __shfl_down(dist, off, 64);
        if ((tid & 63) == 0) partial[tid >> 6] = dist;
    }
    __syncthreads();
    if (tid == 0) {
        float s = partial[0] + partial[1] + partial[2] + partial[3];
        atomicAdd(out, s * (1.0f / 32768.0f));
    }
}

extern "C" void kernel_launch(void* const* d_in, const int* in_sizes, int n_in,
                              void* d_out, int out_size, void* d_ws, size_t ws_size,
                              hipStream_t stream) {
    const float* f  = (const float*)d_in[0];
    const float* f_ = (const float*)d_in[1];
    float* out = (float*)d_out;

    const size_t MB = 1048576;
    if (ws_size >= 5 * MB) {
        bf8*      fA  = (bf8*)d_ws;                        // f  as A-role, 1 MB
        bf8*      fB  = (bf8*)((char*)d_ws + 1 * MB);      // f  as B-role
        bf8*      gA  = (bf8*)((char*)d_ws + 2 * MB);      // f_ as A-role
        bf8*      gB  = (bf8*)((char*)d_ws + 3 * MB);      // f_ as B-role
        unsigned* seg = (unsigned*)((char*)d_ws + 4 * MB); // 256 KB
        pack_mfma<<<256, 256, 0, stream>>>(f, f_, fA, fB, gA, gB, seg, out);
        chamfer_mfma<<<1024, 256, 0, stream>>>(fA, fB, gA, gB, seg);
        finalize_mfma<<<64, 1024, 0, stream>>>(seg, out);
    } else if (ws_size >= 3 * MB) {
        float4* pk = (float4*)d_ws;
        float4* pr = (float4*)((char*)d_ws + 1 * MB);
        float*  sg = (float*)((char*)d_ws + 2 * MB);
        pack_pk<<<256, 256, 0, stream>>>(f, f_, pk, (float*)pr, out);
        chamfer_pk<<<1024, 512, 0, stream>>>(pk, pr, sg);
        finalize_pk<<<64, 1024, 0, stream>>>(pk, sg, out);
    } else {
        zero_out_kernel<<<1, 1, 0, stream>>>(out);
        chamfer_fallback<<<256, 1024, 0, stream>>>(f, f_, out);
    }
}

// Round 9
// 87.614 us; speedup vs baseline: 1.3054x; 1.2466x over previous
//
#include <hip/hip_runtime.h>

#define NPTS  8192
#define BATCH 4

typedef short  bf8    __attribute__((ext_vector_type(8)));   // 8 bf16 = 4 VGPRs
typedef float  f32x16 __attribute__((ext_vector_type(16)));
typedef float  v2f    __attribute__((ext_vector_type(2)));

__device__ inline unsigned short bf16_rne(float x) {
    unsigned u = __float_as_uint(x);
    unsigned r = (u + 0x7FFFu + ((u >> 16) & 1u)) >> 16;   // round-nearest-even
    return (unsigned short)r;
}
__device__ inline float bf16_to_f(unsigned short h) {
    return __uint_as_float(((unsigned)h) << 16);
}
// Order-preserving float<->uint encode so atomicMax(uint) == float max.
__device__ inline unsigned fenc(float x) {
    unsigned b = __float_as_uint(x);
    return (b & 0x80000000u) ? ~b : (b | 0x80000000u);
}
__device__ inline float fdec(unsigned k) {
    unsigned b = (k & 0x80000000u) ? (k ^ 0x80000000u) : ~k;
    return __uint_as_float(b);
}

// ============================================================================
// MFMA path: v_mfma_f32_32x32x16_bf16, layouts VERIFIED end-to-end in R8
// (absmax 0.0). ||s-d||^2 = -2*(s.d + w_s + w_d), w_p = -0.5*||p||^2.
// K-slots (16): A = [xh yh zh xl yl zl xh yh | zh 1 1 wh wl 0 0 0]
//               B = [xh yh zh xh yh zh xl yl | zl wh wl 1 1 0 0 0]
//   => C[n,m] = s.d (split-bf16) + w_s + w_d;  dist = max(-2C, 0).
// A/B: point = lane&31, k = (lane>>5)*8 + j. C/D: col = lane&31,
// row = (reg&3) + 8*(reg>>2) + 4*(lane>>5).
// R9 vs R8: wave tile cut 4 -> 2 n-tiles (rmax[2]=32 VGPRs) to kill the
// scratch spill R8's counters showed (40MB traffic = whole 55us), and
// __launch_bounds__(256,3) for a 170-VGPR budget / 3 blocks/CU.
// ============================================================================

__global__ void pack_mfma(const float* __restrict__ f, const float* __restrict__ f_,
                          bf8* __restrict__ fA, bf8* __restrict__ fB,
                          bf8* __restrict__ gA, bf8* __restrict__ gB,
                          unsigned* __restrict__ seg, float* __restrict__ out) {
    int j = blockIdx.x * blockDim.x + threadIdx.x;   // 0..65535
    if (j == 0) out[0] = 0.0f;                       // d_out poisoned 0xAA
    seg[j] = 0u;                                     // < fenc of any real value
    int cloud = j >> 15;
    int idx   = j & 32767;                           // b*8192 + p
    const float* src = cloud ? f_ : f;
    float x = src[idx * 3 + 0], y = src[idx * 3 + 1], z = src[idx * 3 + 2];
    float w = -0.5f * (x * x + y * y + z * z);
    unsigned short xh = bf16_rne(x), yh = bf16_rne(y), zh = bf16_rne(z);
    unsigned short xl = bf16_rne(x - bf16_to_f(xh));
    unsigned short yl = bf16_rne(y - bf16_to_f(yh));
    unsigned short zl = bf16_rne(z - bf16_to_f(zh));
    unsigned short wh = bf16_rne(w);
    unsigned short wl = bf16_rne(w - bf16_to_f(wh));
    const short ONE = (short)0x3F80;                 // bf16 1.0

    bf8 A0, A1, B0, B1;
    A0[0]=(short)xh; A0[1]=(short)yh; A0[2]=(short)zh; A0[3]=(short)xl;
    A0[4]=(short)yl; A0[5]=(short)zl; A0[6]=(short)xh; A0[7]=(short)yh;
    A1[0]=(short)zh; A1[1]=ONE;       A1[2]=ONE;       A1[3]=(short)wh;
    A1[4]=(short)wl; A1[5]=0;         A1[6]=0;         A1[7]=0;
    B0[0]=(short)xh; B0[1]=(short)yh; B0[2]=(short)zh; B0[3]=(short)xh;
    B0[4]=(short)yh; B0[5]=(short)zh; B0[6]=(short)xl; B0[7]=(short)yl;
    B1[0]=(short)zl; B1[1]=(short)wh; B1[2]=(short)wl; B1[3]=ONE;
    B1[4]=ONE;       B1[5]=0;         B1[6]=0;         B1[7]=0;

    int b = idx >> 13, p = idx & 8191;
    int t = p >> 5, li = p & 31;                     // 32-point tiles
    size_t base = ((size_t)(b * 256 + t)) * 64;
    bf8* Adst = cloud ? gA : fA;
    bf8* Bdst = cloud ? gB : fB;
    Adst[base + li]      = A0;                       // khalf 0
    Adst[base + 32 + li] = A1;                       // khalf 1
    Bdst[base + li]      = B0;
    Bdst[base + 32 + li] = B1;
}

// 2048 blocks x 256 thr (4 waves). Block = (pass, b, nblk: 256 rows, mseg:
// 1024 m = 32 tiles staged in 32 KB LDS). Wave holds 2 n-tiles (64 rows).
// Per pair-iter: 2 ds_read_b128, 4 MFMA(32x32x16), 32 v_max3.
// Epilogue: 5-step butterfly row-max over 32 cols -> atomicMax(enc) into seg.
__global__ __launch_bounds__(256, 3) void chamfer_mfma(
        const bf8* __restrict__ fA, const bf8* __restrict__ fB,
        const bf8* __restrict__ gA, const bf8* __restrict__ gB,
        unsigned* __restrict__ seg) {
    __shared__ bf8 lbs[2048];                        // 32 m-tiles = 32 KB

    int tid  = threadIdx.x;
    int wv   = tid >> 6, lane = tid & 63;
    int bx   = blockIdx.x;                           // [0, 2048)
    int mseg = bx & 7;
    int nblk = (bx >> 3) & 31;
    int b    = (bx >> 8) & 3;
    int pass = bx >> 10;                             // {0,1} — grid-exact

    const bf8* __restrict__ Af = pass ? gA : fA;     // rows (query side)
    const bf8* __restrict__ Bf = pass ? fB : gB;     // cols (target side)

    // Stage this block's 32 B-tiles (1024 m-points) into LDS: 8x 16B/thread.
    const bf8* __restrict__ bp = Bf + ((size_t)(b * 256 + mseg * 32)) * 64;
#pragma unroll
    for (int k = 0; k < 8; ++k) lbs[k * 256 + tid] = bp[k * 256 + tid];

    // This wave's 2 n-tiles (64 rows).
    bf8 a[2];
    f32x16 rmax[2];
    int nt_loc = nblk * 8 + wv * 2;                  // tile idx within batch
#pragma unroll
    for (int s = 0; s < 2; ++s) {
        a[s] = Af[(size_t)(b * 256 + nt_loc + s) * 64 + lane];
        rmax[s] = (f32x16)(-3.0e38f);
    }
    __syncthreads();

    f32x16 zc = (f32x16)(0.0f);
    for (int i = 0; i < 16; ++i) {                   // 16 pair-iters = 32 tiles
        bf8 qa = lbs[(2 * i) * 64 + lane];
        bf8 qb = lbs[(2 * i + 1) * 64 + lane];
#pragma unroll
        for (int s = 0; s < 2; ++s) {
            f32x16 d0 = __builtin_amdgcn_mfma_f32_32x32x16_bf16(a[s], qa, zc, 0, 0, 0);
            f32x16 d1 = __builtin_amdgcn_mfma_f32_32x32x16_bf16(a[s], qb, zc, 0, 0, 0);
            rmax[s] = __builtin_elementwise_max(
                          __builtin_elementwise_max(rmax[s], d0), d1);  // v_max3
        }
    }

    // Row-max across 32 cols (col = lane&31): 5-step butterfly.
#pragma unroll
    for (int s = 0; s < 2; ++s) {
#pragma unroll
        for (int m = 1; m < 32; m <<= 1) {
            f32x16 o;
#pragma unroll
            for (int r = 0; r < 16; ++r) o[r] = __shfl_xor(rmax[s][r], m, 64);
            rmax[s] = __builtin_elementwise_max(rmax[s], o);
        }
    }

    // C/D row = (reg&3) + 8*(reg>>2) + 4*(lane>>5); lanes 0 and 32 write.
    if ((lane & 31) == 0) {
        int rbase = (lane >> 5) * 4;
        unsigned* sg = seg + (size_t)(pass * 4 + b) * NPTS;
#pragma unroll
        for (int s = 0; s < 2; ++s) {
            int n0 = (nt_loc + s) * 32;
#pragma unroll
            for (int r = 0; r < 16; ++r) {
                int row = (r & 3) + 8 * (r >> 2) + rbase;
                atomicMax(&sg[n0 + row], fenc(rmax[s][r]));
            }
        }
    }
}

__global__ __launch_bounds__(1024) void finalize_mfma(
        const unsigned* __restrict__ seg, float* __restrict__ out) {
    __shared__ float partial[16];
    int j = blockIdx.x * 1024 + threadIdx.x;         // (pass*4+b)*8192 + n
    float emax = fdec(seg[j]);
    float dist = fmaxf(-2.0f * emax, 0.0f);          // C = s.d + w_s + w_d
    for (int off = 32; off > 0; off >>= 1)
        dist += __shfl_down(dist, off, 64);
    int lane = threadIdx.x & 63, wv = threadIdx.x >> 6;
    if (lane == 0) partial[wv] = dist;
    __syncthreads();
    if (threadIdx.x < 16) {
        float s = partial[threadIdx.x];
        for (int off = 8; off > 0; off >>= 1)
            s += __shfl_down(s, off, 64);
        if (threadIdx.x == 0) atomicAdd(out, s * (1.0f / 32768.0f));
    }
}

// ============================================================================
// Fallback 1 (ws >= 3MB): verified R4 packed-fp32 path (45.7 us main).
// ============================================================================

__global__ void pack_pk(const float* __restrict__ f, const float* __restrict__ f_,
                        float4* __restrict__ pk, float* __restrict__ prf,
                        float* __restrict__ out) {
    int j = blockIdx.x * blockDim.x + threadIdx.x;
    if (j == 0) out[0] = 0.0f;
    const float* src = (j >= 32768) ? f_ : f;
    int idx = j & 32767;
    float x = src[idx * 3 + 0], y = src[idx * 3 + 1], z = src[idx * 3 + 2];
    float w = -0.5f * (x * x + y * y + z * z);
    pk[j] = make_float4(x, y, z, w);
    int  slot = j & 1;
    long base = (long)(j >> 1) * 8;
    prf[base + 0 + slot] = x;
    prf[base + 2 + slot] = y;
    prf[base + 4 + slot] = z;
    prf[base + 6 + slot] = w;
}

__global__ __launch_bounds__(512, 8) void chamfer_pk(
        const float4* __restrict__ pk, const float4* __restrict__ pr,
        float* __restrict__ seg) {
    __shared__ float red[8][256];
    int tid  = threadIdx.x;
    int wv   = __builtin_amdgcn_readfirstlane(tid >> 6);
    int lane = tid & 63;
    int bx   = blockIdx.x;
    int tile = bx & 31;
    int b    = (bx >> 5) & 3;
    int dir  = (bx >> 7) & 1;
    int mq   = bx >> 8;

    const float4* __restrict__ A = pk + ((size_t)dir * BATCH + b) * NPTS;
    int n_base = tile * 256;
    v2f px[4], py[4], pz[4], e2[4];
#pragma unroll
    for (int r = 0; r < 4; ++r) {
        float4 p = A[n_base + lane + 64 * r];
        px[r] = (v2f){p.x, p.x};
        py[r] = (v2f){p.y, p.y};
        pz[r] = (v2f){p.z, p.z};
        e2[r] = (v2f){-1e30f, -1e30f};
    }
    int sb_m = (1 - dir) * BATCH + b;
    const float4* __restrict__ mp =
        pr + ((size_t)sb_m * 4096 + mq * 1024 + wv * 128) * 2;

    for (int i = 0; i < 128; i += 4) {
#pragma unroll
        for (int u = 0; u < 4; ++u) {
            float4 qa = mp[(i + u) * 2 + 0];
            float4 qb = mp[(i + u) * 2 + 1];
            v2f qx = (v2f){qa.x, qa.y};
            v2f qy = (v2f){qa.z, qa.w};
            v2f qz = (v2f){qb.x, qb.y};
            v2f qw = (v2f){qb.z, qb.w};
#pragma unroll
            for (int r = 0; r < 4; ++r) {
                v2f c = __builtin_elementwise_fma(px[r], qx, qw);
                c = __builtin_elementwise_fma(py[r], qy, c);
                c = __builtin_elementwise_fma(pz[r], qz, c);
                e2[r] = __builtin_elementwise_max(e2[r], c);
            }
        }
    }
#pragma unroll
    for (int r = 0; r < 4; ++r)
        red[wv][lane + 64 * r] = fmaxf(e2[r].x, e2[r].y);
    __syncthreads();
    if (tid < 256) {
        float emax = red[0][tid];
#pragma unroll
        for (int ww = 1; ww < 8; ++ww) emax = fmaxf(emax, red[ww][tid]);
        seg[mq * (2 * BATCH * NPTS) + dir * (BATCH * NPTS) + b * NPTS
            + n_base + tid] = emax;
    }
}

__global__ __launch_bounds__(1024) void finalize_pk(
        const float4* __restrict__ pk, const float* __restrict__ seg,
        float* __restrict__ out) {
    __shared__ float partial[16];
    int j = blockIdx.x * 1024 + threadIdx.x;
    float emax = seg[j];
#pragma unroll
    for (int q = 1; q < 4; ++q) emax = fmaxf(emax, seg[q * 65536 + j]);
    float dist = fmaxf(-2.0f * (emax + pk[j].w), 0.0f);
    for (int off = 32; off > 0; off >>= 1)
        dist += __shfl_down(dist, off, 64);
    int lane = threadIdx.x & 63, wv = threadIdx.x >> 6;
    if (lane == 0) partial[wv] = dist;
    __syncthreads();
    if (threadIdx.x < 16) {
        float s = partial[threadIdx.x];
        for (int off = 8; off > 0; off >>= 1)
            s += __shfl_down(s, off, 64);
        if (threadIdx.x == 0) atomicAdd(out, s * (1.0f / 32768.0f));
    }
}

// ============================================================================
// Fallback 2 (no ws): verified R2 kernel.
// ============================================================================

__global__ void zero_out_kernel(float* __restrict__ out) { out[0] = 0.0f; }

__global__ __launch_bounds__(1024) void chamfer_fallback(
        const float* __restrict__ f, const float* __restrict__ f_,
        float* __restrict__ out) {
    __shared__ float wlds[NPTS];
    __shared__ float red[16][256];
    __shared__ float partial[4];
    int tid  = threadIdx.x;
    int wv   = __builtin_amdgcn_readfirstlane(tid >> 6);
    int lane = tid & 63;
    int bx   = blockIdx.x;
    int dir  = bx >> 7;
    int b    = (bx >> 5) & 3;
    int tile = bx & 31;
    int n_base = tile * 256;
    const float* __restrict__ A  = dir ? f_ : f;
    const float* __restrict__ Bm = dir ? f  : f_;
    const float* an = A  + (size_t)b * NPTS * 3;
    const float* bm = Bm + (size_t)b * NPTS * 3;
    for (int i = tid; i < NPTS; i += 1024) {
        float x = bm[i * 3 + 0], y = bm[i * 3 + 1], z = bm[i * 3 + 2];
        wlds[i] = -0.5f * (x * x + y * y + z * z);
    }
    float xn[4], yn[4], zn[4];
#pragma unroll
    for (int r = 0; r < 4; ++r) {
        int n = n_base + lane + 64 * r;
        xn[r] = an[n * 3 + 0]; yn[r] = an[n * 3 + 1]; zn[r] = an[n * 3 + 2];
    }
    __syncthreads();
    float e[4];
#pragma unroll
    for (int r = 0; r < 4; ++r) e[r] = -1e30f;
    int m0 = wv * (NPTS / 16);
#pragma unroll 4
    for (int i = 0; i < NPTS / 16; ++i) {
        int m = m0 + i;
        float qx = bm[m * 3 + 0], qy = bm[m * 3 + 1], qz = bm[m * 3 + 2];
        float qw = wlds[m];
#pragma unroll
        for (int r = 0; r < 4; ++r) {
            float c = fmaf(zn[r], qz, fmaf(yn[r], qy, fmaf(xn[r], qx, qw)));
            e[r] = fmaxf(e[r], c);
        }
    }
#pragma unroll
    for (int r = 0; r < 4; ++r) red[wv][lane + 64 * r] = e[r];
    __syncthreads();
    if (tid < 256) {
        float emax = red[0][tid];
#pragma unroll
        for (int ww = 1; ww < 16; ++ww) emax = fmaxf(emax, red[ww][tid]);
        int n = n_base + tid;
        float x = an[n * 3 + 0], y = an[n * 3 + 1], z = an[n * 3 + 2];
        float dist = fmaxf(x * x + y * y + z * z - 2.0f * emax, 0.0f);
        for (int off = 32; off > 0; off >>= 1)
            dist += __shfl_down(dist, off, 64);
        if ((tid & 63) == 0) partial[tid >> 6] = dist;
    }
    __syncthreads();
    if (tid == 0) {
        float s = partial[0] + partial[1] + partial[2] + partial[3];
        atomicAdd(out, s * (1.0f / 32768.0f));
    }
}

extern "C" void kernel_launch(void* const* d_in, const int* in_sizes, int n_in,
                              void* d_out, int out_size, void* d_ws, size_t ws_size,
                              hipStream_t stream) {
    const float* f  = (const float*)d_in[0];
    const float* f_ = (const float*)d_in[1];
    float* out = (float*)d_out;

    const size_t MB = 1048576;
    if (ws_size >= 5 * MB) {
        bf8*      fA  = (bf8*)d_ws;                        // f  as A-role, 1 MB
        bf8*      fB  = (bf8*)((char*)d_ws + 1 * MB);      // f  as B-role
        bf8*      gA  = (bf8*)((char*)d_ws + 2 * MB);      // f_ as A-role
        bf8*      gB  = (bf8*)((char*)d_ws + 3 * MB);      // f_ as B-role
        unsigned* seg = (unsigned*)((char*)d_ws + 4 * MB); // 256 KB
        pack_mfma<<<256, 256, 0, stream>>>(f, f_, fA, fB, gA, gB, seg, out);
        chamfer_mfma<<<2048, 256, 0, stream>>>(fA, fB, gA, gB, seg);
        finalize_mfma<<<64, 1024, 0, stream>>>(seg, out);
    } else if (ws_size >= 3 * MB) {
        float4* pk = (float4*)d_ws;
        float4* pr = (float4*)((char*)d_ws + 1 * MB);
        float*  sg = (float*)((char*)d_ws + 2 * MB);
        pack_pk<<<256, 256, 0, stream>>>(f, f_, pk, (float*)pr, out);
        chamfer_pk<<<1024, 512, 0, stream>>>(pk, pr, sg);
        finalize_pk<<<64, 1024, 0, stream>>>(pk, sg, out);
    } else {
        zero_out_kernel<<<1, 1, 0, stream>>>(out);
        chamfer_fallback<<<256, 1024, 0, stream>>>(f, f_, out);
    }
}

// Round 10
// 84.127 us; speedup vs baseline: 1.3595x; 1.0414x over previous
//
#include <hip/hip_runtime.h>

#define NPTS  8192
#define BATCH 4

typedef short  bf8    __attribute__((ext_vector_type(8)));   // 8 bf16 = 4 VGPRs
typedef float  f32x16 __attribute__((ext_vector_type(16)));
typedef float  v2f    __attribute__((ext_vector_type(2)));

__device__ inline unsigned short bf16_rne(float x) {
    unsigned u = __float_as_uint(x);
    unsigned r = (u + 0x7FFFu + ((u >> 16) & 1u)) >> 16;   // round-nearest-even
    return (unsigned short)r;
}
__device__ inline float bf16_to_f(unsigned short h) {
    return __uint_as_float(((unsigned)h) << 16);
}
// Order-preserving float<->uint encode so atomicMax(uint) == float max.
__device__ inline unsigned fenc(float x) {
    unsigned b = __float_as_uint(x);
    return (b & 0x80000000u) ? ~b : (b | 0x80000000u);
}
__device__ inline float fdec(unsigned k) {
    unsigned b = (k & 0x80000000u) ? (k ^ 0x80000000u) : ~k;
    return __uint_as_float(b);
}

// ============================================================================
// MFMA path: v_mfma_f32_32x32x16_bf16, layouts VERIFIED end-to-end (R8/R9
// absmax 0.0). ||s-d||^2 = -2*(s.d + w_s + w_d), w_p = -0.5*||p||^2.
// K-slots (16): A = [xh yh zh xl yl zl xh yh | zh 1 1 wh wl 0 0 0]
//               B = [xh yh zh xh yh zh xl yl | zl wh wl 1 1 0 0 0]
//   => C[n,m] = s.d (split-bf16) + w_s + w_d;  dist = max(-2C, 0).
// A/B: point = lane&31, k = (lane>>5)*8 + j. C/D: col = lane&31,
// row = (reg&3) + 8*(reg>>2) + 4*(lane>>5).
// R10 vs R9: (a) mseg 8->4 with a 2-chunk loop per block -> butterfly epilogue
// + atomics amortized over 2x more K-work; (b) explicit ds_read prefetch of
// next iter's B-tiles -> LDS latency off the MFMA->max3 dependency chain.
// Timing note: harness poisons the full 256MB d_ws every iter (~42us fill,
// visible as fillBufferAligned in rocprof) — fixed floor in dur_us.
// ============================================================================

__global__ void pack_mfma(const float* __restrict__ f, const float* __restrict__ f_,
                          bf8* __restrict__ fA, bf8* __restrict__ fB,
                          bf8* __restrict__ gA, bf8* __restrict__ gB,
                          unsigned* __restrict__ seg, float* __restrict__ out) {
    int j = blockIdx.x * blockDim.x + threadIdx.x;   // 0..65535
    if (j == 0) out[0] = 0.0f;                       // d_out poisoned 0xAA
    seg[j] = 0u;                                     // < fenc of any real value
    int cloud = j >> 15;
    int idx   = j & 32767;                           // b*8192 + p
    const float* src = cloud ? f_ : f;
    float x = src[idx * 3 + 0], y = src[idx * 3 + 1], z = src[idx * 3 + 2];
    float w = -0.5f * (x * x + y * y + z * z);
    unsigned short xh = bf16_rne(x), yh = bf16_rne(y), zh = bf16_rne(z);
    unsigned short xl = bf16_rne(x - bf16_to_f(xh));
    unsigned short yl = bf16_rne(y - bf16_to_f(yh));
    unsigned short zl = bf16_rne(z - bf16_to_f(zh));
    unsigned short wh = bf16_rne(w);
    unsigned short wl = bf16_rne(w - bf16_to_f(wh));
    const short ONE = (short)0x3F80;                 // bf16 1.0

    bf8 A0, A1, B0, B1;
    A0[0]=(short)xh; A0[1]=(short)yh; A0[2]=(short)zh; A0[3]=(short)xl;
    A0[4]=(short)yl; A0[5]=(short)zl; A0[6]=(short)xh; A0[7]=(short)yh;
    A1[0]=(short)zh; A1[1]=ONE;       A1[2]=ONE;       A1[3]=(short)wh;
    A1[4]=(short)wl; A1[5]=0;         A1[6]=0;         A1[7]=0;
    B0[0]=(short)xh; B0[1]=(short)yh; B0[2]=(short)zh; B0[3]=(short)xh;
    B0[4]=(short)yh; B0[5]=(short)zh; B0[6]=(short)xl; B0[7]=(short)yl;
    B1[0]=(short)zl; B1[1]=(short)wh; B1[2]=(short)wl; B1[3]=ONE;
    B1[4]=ONE;       B1[5]=0;         B1[6]=0;         B1[7]=0;

    int b = idx >> 13, p = idx & 8191;
    int t = p >> 5, li = p & 31;                     // 32-point tiles
    size_t base = ((size_t)(b * 256 + t)) * 64;
    bf8* Adst = cloud ? gA : fA;
    bf8* Bdst = cloud ? gB : fB;
    Adst[base + li]      = A0;                       // khalf 0
    Adst[base + 32 + li] = A1;                       // khalf 1
    Bdst[base + li]      = B0;
    Bdst[base + 32 + li] = B1;
}

// 1024 blocks x 256 thr (4 waves). Block = (pass, b, nblk: 256 rows, mseg:
// 2048 m in TWO 1024-m chunks staged in 32 KB LDS). Wave holds 2 n-tiles.
// Per iter: 2 prefetched ds_read_b128, 4 MFMA(32x32x16), 32 v_max3.
// Epilogue (once per block): 5-step butterfly over 32 cols -> atomicMax(enc).
__global__ __launch_bounds__(256, 3) void chamfer_mfma(
        const bf8* __restrict__ fA, const bf8* __restrict__ fB,
        const bf8* __restrict__ gA, const bf8* __restrict__ gB,
        unsigned* __restrict__ seg) {
    __shared__ bf8 lbs[2048];                        // 32 m-tiles = 32 KB

    int tid  = threadIdx.x;
    int wv   = tid >> 6, lane = tid & 63;
    int bx   = blockIdx.x;                           // [0, 1024)
    int mseg = bx & 3;
    int nblk = (bx >> 2) & 31;
    int b    = (bx >> 7) & 3;
    int pass = bx >> 9;                              // {0,1}

    const bf8* __restrict__ Af = pass ? gA : fA;     // rows (query side)
    const bf8* __restrict__ Bf = pass ? fB : gB;     // cols (target side)

    // This wave's 2 n-tiles (64 rows) — load first, overlaps with staging.
    bf8 a[2];
    f32x16 rmax[2];
    int nt_loc = nblk * 8 + wv * 2;                  // tile idx within batch
#pragma unroll
    for (int s = 0; s < 2; ++s) {
        a[s] = Af[(size_t)(b * 256 + nt_loc + s) * 64 + lane];
        rmax[s] = (f32x16)(-3.0e38f);
    }

    f32x16 zc = (f32x16)(0.0f);
    for (int c = 0; c < 2; ++c) {
        // Stage this chunk's 32 B-tiles (1024 m-points): 8x 16B/thread.
        const bf8* __restrict__ bp =
            Bf + ((size_t)(b * 256 + mseg * 64 + c * 32)) * 64;
        if (c) __syncthreads();                      // lbs reuse fence
#pragma unroll
        for (int k = 0; k < 8; ++k) lbs[k * 256 + tid] = bp[k * 256 + tid];
        __syncthreads();

        // 16 pair-iters with 1-deep ds_read prefetch.
        bf8 qa = lbs[lane];
        bf8 qb = lbs[64 + lane];
#pragma unroll 2
        for (int i = 0; i < 16; ++i) {
            int ip = (i + 1) & 15;                   // wrap: last is harmless
            bf8 na = lbs[ip * 128 + lane];
            bf8 nb = lbs[ip * 128 + 64 + lane];
            f32x16 d0 = __builtin_amdgcn_mfma_f32_32x32x16_bf16(a[0], qa, zc, 0, 0, 0);
            f32x16 d1 = __builtin_amdgcn_mfma_f32_32x32x16_bf16(a[0], qb, zc, 0, 0, 0);
            f32x16 d2 = __builtin_amdgcn_mfma_f32_32x32x16_bf16(a[1], qa, zc, 0, 0, 0);
            f32x16 d3 = __builtin_amdgcn_mfma_f32_32x32x16_bf16(a[1], qb, zc, 0, 0, 0);
            rmax[0] = __builtin_elementwise_max(
                          __builtin_elementwise_max(rmax[0], d0), d1);  // v_max3
            rmax[1] = __builtin_elementwise_max(
                          __builtin_elementwise_max(rmax[1], d2), d3);
            qa = na; qb = nb;
        }
    }

    // Row-max across 32 cols (col = lane&31): 5-step butterfly.
#pragma unroll
    for (int s = 0; s < 2; ++s) {
#pragma unroll
        for (int m = 1; m < 32; m <<= 1) {
            f32x16 o;
#pragma unroll
            for (int r = 0; r < 16; ++r) o[r] = __shfl_xor(rmax[s][r], m, 64);
            rmax[s] = __builtin_elementwise_max(rmax[s], o);
        }
    }

    // C/D row = (reg&3) + 8*(reg>>2) + 4*(lane>>5); lanes 0 and 32 write.
    if ((lane & 31) == 0) {
        int rbase = (lane >> 5) * 4;
        unsigned* sg = seg + (size_t)(pass * 4 + b) * NPTS;
#pragma unroll
        for (int s = 0; s < 2; ++s) {
            int n0 = (nt_loc + s) * 32;
#pragma unroll
            for (int r = 0; r < 16; ++r) {
                int row = (r & 3) + 8 * (r >> 2) + rbase;
                atomicMax(&sg[n0 + row], fenc(rmax[s][r]));
            }
        }
    }
}

__global__ __launch_bounds__(1024) void finalize_mfma(
        const unsigned* __restrict__ seg, float* __restrict__ out) {
    __shared__ float partial[16];
    int j = blockIdx.x * 1024 + threadIdx.x;         // (pass*4+b)*8192 + n
    float emax = fdec(seg[j]);
    float dist = fmaxf(-2.0f * emax, 0.0f);          // C = s.d + w_s + w_d
    for (int off = 32; off > 0; off >>= 1)
        dist += __shfl_down(dist, off, 64);
    int lane = threadIdx.x & 63, wv = threadIdx.x >> 6;
    if (lane == 0) partial[wv] = dist;
    __syncthreads();
    if (threadIdx.x < 16) {
        float s = partial[threadIdx.x];
        for (int off = 8; off > 0; off >>= 1)
            s += __shfl_down(s, off, 64);
        if (threadIdx.x == 0) atomicAdd(out, s * (1.0f / 32768.0f));
    }
}

// ============================================================================
// Fallback 1 (ws >= 3MB): verified R4 packed-fp32 path (45.7 us main).
// ============================================================================

__global__ void pack_pk(const float* __restrict__ f, const float* __restrict__ f_,
                        float4* __restrict__ pk, float* __restrict__ prf,
                        float* __restrict__ out) {
    int j = blockIdx.x * blockDim.x + threadIdx.x;
    if (j == 0) out[0] = 0.0f;
    const float* src = (j >= 32768) ? f_ : f;
    int idx = j & 32767;
    float x = src[idx * 3 + 0], y = src[idx * 3 + 1], z = src[idx * 3 + 2];
    float w = -0.5f * (x * x + y * y + z * z);
    pk[j] = make_float4(x, y, z, w);
    int  slot = j & 1;
    long base = (long)(j >> 1) * 8;
    prf[base + 0 + slot] = x;
    prf[base + 2 + slot] = y;
    prf[base + 4 + slot] = z;
    prf[base + 6 + slot] = w;
}

__global__ __launch_bounds__(512, 8) void chamfer_pk(
        const float4* __restrict__ pk, const float4* __restrict__ pr,
        float* __restrict__ seg) {
    __shared__ float red[8][256];
    int tid  = threadIdx.x;
    int wv   = __builtin_amdgcn_readfirstlane(tid >> 6);
    int lane = tid & 63;
    int bx   = blockIdx.x;
    int tile = bx & 31;
    int b    = (bx >> 5) & 3;
    int dir  = (bx >> 7) & 1;
    int mq   = bx >> 8;

    const float4* __restrict__ A = pk + ((size_t)dir * BATCH + b) * NPTS;
    int n_base = tile * 256;
    v2f px[4], py[4], pz[4], e2[4];
#pragma unroll
    for (int r = 0; r < 4; ++r) {
        float4 p = A[n_base + lane + 64 * r];
        px[r] = (v2f){p.x, p.x};
        py[r] = (v2f){p.y, p.y};
        pz[r] = (v2f){p.z, p.z};
        e2[r] = (v2f){-1e30f, -1e30f};
    }
    int sb_m = (1 - dir) * BATCH + b;
    const float4* __restrict__ mp =
        pr + ((size_t)sb_m * 4096 + mq * 1024 + wv * 128) * 2;

    for (int i = 0; i < 128; i += 4) {
#pragma unroll
        for (int u = 0; u < 4; ++u) {
            float4 qa = mp[(i + u) * 2 + 0];
            float4 qb = mp[(i + u) * 2 + 1];
            v2f qx = (v2f){qa.x, qa.y};
            v2f qy = (v2f){qa.z, qa.w};
            v2f qz = (v2f){qb.x, qb.y};
            v2f qw = (v2f){qb.z, qb.w};
#pragma unroll
            for (int r = 0; r < 4; ++r) {
                v2f c = __builtin_elementwise_fma(px[r], qx, qw);
                c = __builtin_elementwise_fma(py[r], qy, c);
                c = __builtin_elementwise_fma(pz[r], qz, c);
                e2[r] = __builtin_elementwise_max(e2[r], c);
            }
        }
    }
#pragma unroll
    for (int r = 0; r < 4; ++r)
        red[wv][lane + 64 * r] = fmaxf(e2[r].x, e2[r].y);
    __syncthreads();
    if (tid < 256) {
        float emax = red[0][tid];
#pragma unroll
        for (int ww = 1; ww < 8; ++ww) emax = fmaxf(emax, red[ww][tid]);
        seg[mq * (2 * BATCH * NPTS) + dir * (BATCH * NPTS) + b * NPTS
            + n_base + tid] = emax;
    }
}

__global__ __launch_bounds__(1024) void finalize_pk(
        const float4* __restrict__ pk, const float* __restrict__ seg,
        float* __restrict__ out) {
    __shared__ float partial[16];
    int j = blockIdx.x * 1024 + threadIdx.x;
    float emax = seg[j];
#pragma unroll
    for (int q = 1; q < 4; ++q) emax = fmaxf(emax, seg[q * 65536 + j]);
    float dist = fmaxf(-2.0f * (emax + pk[j].w), 0.0f);
    for (int off = 32; off > 0; off >>= 1)
        dist += __shfl_down(dist, off, 64);
    int lane = threadIdx.x & 63, wv = threadIdx.x >> 6;
    if (lane == 0) partial[wv] = dist;
    __syncthreads();
    if (threadIdx.x < 16) {
        float s = partial[threadIdx.x];
        for (int off = 8; off > 0; off >>= 1)
            s += __shfl_down(s, off, 64);
        if (threadIdx.x == 0) atomicAdd(out, s * (1.0f / 32768.0f));
    }
}

// ============================================================================
// Fallback 2 (no ws): verified R2 kernel.
// ============================================================================

__global__ void zero_out_kernel(float* __restrict__ out) { out[0] = 0.0f; }

__global__ __launch_bounds__(1024) void chamfer_fallback(
        const float* __restrict__ f, const float* __restrict__ f_,
        float* __restrict__ out) {
    __shared__ float wlds[NPTS];
    __shared__ float red[16][256];
    __shared__ float partial[4];
    int tid  = threadIdx.x;
    int wv   = __builtin_amdgcn_readfirstlane(tid >> 6);
    int lane = tid & 63;
    int bx   = blockIdx.x;
    int dir  = bx >> 7;
    int b    = (bx >> 5) & 3;
    int tile = bx & 31;
    int n_base = tile * 256;
    const float* __restrict__ A  = dir ? f_ : f;
    const float* __restrict__ Bm = dir ? f  : f_;
    const float* an = A  + (size_t)b * NPTS * 3;
    const float* bm = Bm + (size_t)b * NPTS * 3;
    for (int i = tid; i < NPTS; i += 1024) {
        float x = bm[i * 3 + 0], y = bm[i * 3 + 1], z = bm[i * 3 + 2];
        wlds[i] = -0.5f * (x * x + y * y + z * z);
    }
    float xn[4], yn[4], zn[4];
#pragma unroll
    for (int r = 0; r < 4; ++r) {
        int n = n_base + lane + 64 * r;
        xn[r] = an[n * 3 + 0]; yn[r] = an[n * 3 + 1]; zn[r] = an[n * 3 + 2];
    }
    __syncthreads();
    float e[4];
#pragma unroll
    for (int r = 0; r < 4; ++r) e[r] = -1e30f;
    int m0 = wv * (NPTS / 16);
#pragma unroll 4
    for (int i = 0; i < NPTS / 16; ++i) {
        int m = m0 + i;
        float qx = bm[m * 3 + 0], qy = bm[m * 3 + 1], qz = bm[m * 3 + 2];
        float qw = wlds[m];
#pragma unroll
        for (int r = 0; r < 4; ++r) {
            float c = fmaf(zn[r], qz, fmaf(yn[r], qy, fmaf(xn[r], qx, qw)));
            e[r] = fmaxf(e[r], c);
        }
    }
#pragma unroll
    for (int r = 0; r < 4; ++r) red[wv][lane + 64 * r] = e[r];
    __syncthreads();
    if (tid < 256) {
        float emax = red[0][tid];
#pragma unroll
        for (int ww = 1; ww < 16; ++ww) emax = fmaxf(emax, red[ww][tid]);
        int n = n_base + tid;
        float x = an[n * 3 + 0], y = an[n * 3 + 1], z = an[n * 3 + 2];
        float dist = fmaxf(x * x + y * y + z * z - 2.0f * emax, 0.0f);
        for (int off = 32; off > 0; off >>= 1)
            dist += __shfl_down(dist, off, 64);
        if ((tid & 63) == 0) partial[tid >> 6] = dist;
    }
    __syncthreads();
    if (tid == 0) {
        float s = partial[0] + partial[1] + partial[2] + partial[3];
        atomicAdd(out, s * (1.0f / 32768.0f));
    }
}

extern "C" void kernel_launch(void* const* d_in, const int* in_sizes, int n_in,
                              void* d_out, int out_size, void* d_ws, size_t ws_size,
                              hipStream_t stream) {
    const float* f  = (const float*)d_in[0];
    const float* f_ = (const float*)d_in[1];
    float* out = (float*)d_out;

    const size_t MB = 1048576;
    if (ws_size >= 5 * MB) {
        bf8*      fA  = (bf8*)d_ws;                        // f  as A-role, 1 MB
        bf8*      fB  = (bf8*)((char*)d_ws + 1 * MB);      // f  as B-role
        bf8*      gA  = (bf8*)((char*)d_ws + 2 * MB);      // f_ as A-role
        bf8*      gB  = (bf8*)((char*)d_ws + 3 * MB);      // f_ as B-role
        unsigned* seg = (unsigned*)((char*)d_ws + 4 * MB); // 256 KB
        pack_mfma<<<256, 256, 0, stream>>>(f, f_, fA, fB, gA, gB, seg, out);
        chamfer_mfma<<<1024, 256, 0, stream>>>(fA, fB, gA, gB, seg);
        finalize_mfma<<<64, 1024, 0, stream>>>(seg, out);
    } else if (ws_size >= 3 * MB) {
        float4* pk = (float4*)d_ws;
        float4* pr = (float4*)((char*)d_ws + 1 * MB);
        float*  sg = (float*)((char*)d_ws + 2 * MB);
        pack_pk<<<256, 256, 0, stream>>>(f, f_, pk, (float*)pr, out);
        chamfer_pk<<<1024, 512, 0, stream>>>(pk, pr, sg);
        finalize_pk<<<64, 1024, 0, stream>>>(pk, sg, out);
    } else {
        zero_out_kernel<<<1, 1, 0, stream>>>(out);
        chamfer_fallback<<<256, 1024, 0, stream>>>(f, f_, out);
    }
}

// Round 11
// 83.943 us; speedup vs baseline: 1.3625x; 1.0022x over previous
//
#include <hip/hip_runtime.h>

#define NPTS  8192
#define BATCH 4

typedef short  bf8    __attribute__((ext_vector_type(8)));   // 8 bf16 = 4 VGPRs
typedef float  f32x16 __attribute__((ext_vector_type(16)));
typedef float  v2f    __attribute__((ext_vector_type(2)));

__device__ inline unsigned short bf16_rne(float x) {
    unsigned u = __float_as_uint(x);
    unsigned r = (u + 0x7FFFu + ((u >> 16) & 1u)) >> 16;   // round-nearest-even
    return (unsigned short)r;
}
__device__ inline float bf16_to_f(unsigned short h) {
    return __uint_as_float(((unsigned)h) << 16);
}
// Order-preserving float<->uint encode so atomicMax(uint) == float max.
__device__ inline unsigned fenc(float x) {
    unsigned b = __float_as_uint(x);
    return (b & 0x80000000u) ? ~b : (b | 0x80000000u);
}
__device__ inline float fdec(unsigned k) {
    unsigned b = (k & 0x80000000u) ? (k ^ 0x80000000u) : ~k;
    return __uint_as_float(b);
}

// ============================================================================
// MFMA path: v_mfma_f32_32x32x16_bf16, layouts VERIFIED end-to-end (R8-R10
// absmax 0.0). ||s-d||^2 = -2*(s.d + w_s + w_d), w_p = -0.5*||p||^2.
// K-slots (16): A = [xh yh zh xl yl zl xh yh | zh 1 1 wh wl 0 0 0]
//               B = [xh yh zh xh yh zh xl yl | zl wh wl 1 1 0 0 0]
//   => C[n,m] = s.d (split-bf16) + w_s + w_d;  dist = max(-2C, 0).
// A/B: point = lane&31, k = (lane>>5)*8 + j. C/D: col = lane&31,
// row = (reg&3) + 8*(reg>>2) + 4*(lane>>5).
// R11 vs R10: 512 blocks x 512 thr, __launch_bounds__(512,4):
//   - grid == 2 x 256 CUs exactly -> no dispatch tail (R10: 1024 @ 3/CU);
//   - 4 waves/SIMD -> enough TLP to co-schedule MFMA + VALU pipes (m114);
//   - d0/d1 reused per n-tile (not d0..d3) -> ~100 live VGPRs, fits the
//     128-VGPR budget without spill (R8's 40MB scratch lesson).
// Timing note: harness poisons 256MB d_ws every iter (~42us fill) — fixed
// floor in dur_us, visible as fillBufferAligned in rocprof.
// ============================================================================

__global__ void pack_mfma(const float* __restrict__ f, const float* __restrict__ f_,
                          bf8* __restrict__ fA, bf8* __restrict__ fB,
                          bf8* __restrict__ gA, bf8* __restrict__ gB,
                          unsigned* __restrict__ seg, float* __restrict__ out) {
    int j = blockIdx.x * blockDim.x + threadIdx.x;   // 0..65535
    if (j == 0) out[0] = 0.0f;                       // d_out poisoned 0xAA
    seg[j] = 0u;                                     // < fenc of any real value
    int cloud = j >> 15;
    int idx   = j & 32767;                           // b*8192 + p
    const float* src = cloud ? f_ : f;
    float x = src[idx * 3 + 0], y = src[idx * 3 + 1], z = src[idx * 3 + 2];
    float w = -0.5f * (x * x + y * y + z * z);
    unsigned short xh = bf16_rne(x), yh = bf16_rne(y), zh = bf16_rne(z);
    unsigned short xl = bf16_rne(x - bf16_to_f(xh));
    unsigned short yl = bf16_rne(y - bf16_to_f(yh));
    unsigned short zl = bf16_rne(z - bf16_to_f(zh));
    unsigned short wh = bf16_rne(w);
    unsigned short wl = bf16_rne(w - bf16_to_f(wh));
    const short ONE = (short)0x3F80;                 // bf16 1.0

    bf8 A0, A1, B0, B1;
    A0[0]=(short)xh; A0[1]=(short)yh; A0[2]=(short)zh; A0[3]=(short)xl;
    A0[4]=(short)yl; A0[5]=(short)zl; A0[6]=(short)xh; A0[7]=(short)yh;
    A1[0]=(short)zh; A1[1]=ONE;       A1[2]=ONE;       A1[3]=(short)wh;
    A1[4]=(short)wl; A1[5]=0;         A1[6]=0;         A1[7]=0;
    B0[0]=(short)xh; B0[1]=(short)yh; B0[2]=(short)zh; B0[3]=(short)xh;
    B0[4]=(short)yh; B0[5]=(short)zh; B0[6]=(short)xl; B0[7]=(short)yl;
    B1[0]=(short)zl; B1[1]=(short)wh; B1[2]=(short)wl; B1[3]=ONE;
    B1[4]=ONE;       B1[5]=0;         B1[6]=0;         B1[7]=0;

    int b = idx >> 13, p = idx & 8191;
    int t = p >> 5, li = p & 31;                     // 32-point tiles
    size_t base = ((size_t)(b * 256 + t)) * 64;
    bf8* Adst = cloud ? gA : fA;
    bf8* Bdst = cloud ? gB : fB;
    Adst[base + li]      = A0;                       // khalf 0
    Adst[base + 32 + li] = A1;                       // khalf 1
    Bdst[base + li]      = B0;
    Bdst[base + 32 + li] = B1;
}

// 512 blocks x 512 thr (8 waves). Block = (pass, b, nblk: 512 rows, mseg:
// 2048 m in TWO 1024-m chunks staged in 32 KB LDS). Wave holds 2 n-tiles.
// Per iter: 2 prefetched ds_read_b128, 4 MFMA(32x32x16) with d0/d1 reuse,
// 32 v_max3. Epilogue: 5-step butterfly over 32 cols -> atomicMax(enc).
__global__ __launch_bounds__(512, 4) void chamfer_mfma(
        const bf8* __restrict__ fA, const bf8* __restrict__ fB,
        const bf8* __restrict__ gA, const bf8* __restrict__ gB,
        unsigned* __restrict__ seg) {
    __shared__ bf8 lbs[2048];                        // 32 m-tiles = 32 KB

    int tid  = threadIdx.x;
    int wv   = tid >> 6, lane = tid & 63;
    int bx   = blockIdx.x;                           // [0, 512)
    int mseg = bx & 3;
    int nblk = (bx >> 2) & 15;
    int b    = (bx >> 6) & 3;
    int pass = bx >> 8;                              // {0,1}

    const bf8* __restrict__ Af = pass ? gA : fA;     // rows (query side)
    const bf8* __restrict__ Bf = pass ? fB : gB;     // cols (target side)

    // This wave's 2 n-tiles (64 rows) — load first, overlaps with staging.
    bf8 a[2];
    f32x16 rmax[2];
    int nt_loc = nblk * 16 + wv * 2;                 // tile idx within batch
#pragma unroll
    for (int s = 0; s < 2; ++s) {
        a[s] = Af[(size_t)(b * 256 + nt_loc + s) * 64 + lane];
        rmax[s] = (f32x16)(-3.0e38f);
    }

    f32x16 zc = (f32x16)(0.0f);
    for (int c = 0; c < 2; ++c) {
        // Stage this chunk's 32 B-tiles (1024 m-points): 4x 16B/thread.
        const bf8* __restrict__ bp =
            Bf + ((size_t)(b * 256 + mseg * 64 + c * 32)) * 64;
        if (c) __syncthreads();                      // lbs reuse fence
#pragma unroll
        for (int k = 0; k < 4; ++k) lbs[k * 512 + tid] = bp[k * 512 + tid];
        __syncthreads();

        // 16 pair-iters with 1-deep ds_read prefetch; d0/d1 reused per n-tile
        // to keep live VGPRs ~100 (128 budget at 4 waves/SIMD).
        bf8 qa = lbs[lane];
        bf8 qb = lbs[64 + lane];
#pragma unroll 2
        for (int i = 0; i < 16; ++i) {
            int ip = (i + 1) & 15;                   // wrap: last is harmless
            bf8 na = lbs[ip * 128 + lane];
            bf8 nb = lbs[ip * 128 + 64 + lane];
            f32x16 d0 = __builtin_amdgcn_mfma_f32_32x32x16_bf16(a[0], qa, zc, 0, 0, 0);
            f32x16 d1 = __builtin_amdgcn_mfma_f32_32x32x16_bf16(a[0], qb, zc, 0, 0, 0);
            rmax[0] = __builtin_elementwise_max(
                          __builtin_elementwise_max(rmax[0], d0), d1);  // v_max3
            d0 = __builtin_amdgcn_mfma_f32_32x32x16_bf16(a[1], qa, zc, 0, 0, 0);
            d1 = __builtin_amdgcn_mfma_f32_32x32x16_bf16(a[1], qb, zc, 0, 0, 0);
            rmax[1] = __builtin_elementwise_max(
                          __builtin_elementwise_max(rmax[1], d0), d1);
            qa = na; qb = nb;
        }
    }

    // Row-max across 32 cols (col = lane&31): 5-step butterfly.
#pragma unroll
    for (int s = 0; s < 2; ++s) {
#pragma unroll
        for (int m = 1; m < 32; m <<= 1) {
            f32x16 o;
#pragma unroll
            for (int r = 0; r < 16; ++r) o[r] = __shfl_xor(rmax[s][r], m, 64);
            rmax[s] = __builtin_elementwise_max(rmax[s], o);
        }
    }

    // C/D row = (reg&3) + 8*(reg>>2) + 4*(lane>>5); lanes 0 and 32 write.
    if ((lane & 31) == 0) {
        int rbase = (lane >> 5) * 4;
        unsigned* sg = seg + (size_t)(pass * 4 + b) * NPTS;
#pragma unroll
        for (int s = 0; s < 2; ++s) {
            int n0 = (nt_loc + s) * 32;
#pragma unroll
            for (int r = 0; r < 16; ++r) {
                int row = (r & 3) + 8 * (r >> 2) + rbase;
                atomicMax(&sg[n0 + row], fenc(rmax[s][r]));
            }
        }
    }
}

__global__ __launch_bounds__(1024) void finalize_mfma(
        const unsigned* __restrict__ seg, float* __restrict__ out) {
    __shared__ float partial[16];
    int j = blockIdx.x * 1024 + threadIdx.x;         // (pass*4+b)*8192 + n
    float emax = fdec(seg[j]);
    float dist = fmaxf(-2.0f * emax, 0.0f);          // C = s.d + w_s + w_d
    for (int off = 32; off > 0; off >>= 1)
        dist += __shfl_down(dist, off, 64);
    int lane = threadIdx.x & 63, wv = threadIdx.x >> 6;
    if (lane == 0) partial[wv] = dist;
    __syncthreads();
    if (threadIdx.x < 16) {
        float s = partial[threadIdx.x];
        for (int off = 8; off > 0; off >>= 1)
            s += __shfl_down(s, off, 64);
        if (threadIdx.x == 0) atomicAdd(out, s * (1.0f / 32768.0f));
    }
}

// ============================================================================
// Fallback 1 (ws >= 3MB): verified R4 packed-fp32 path (45.7 us main).
// ============================================================================

__global__ void pack_pk(const float* __restrict__ f, const float* __restrict__ f_,
                        float4* __restrict__ pk, float* __restrict__ prf,
                        float* __restrict__ out) {
    int j = blockIdx.x * blockDim.x + threadIdx.x;
    if (j == 0) out[0] = 0.0f;
    const float* src = (j >= 32768) ? f_ : f;
    int idx = j & 32767;
    float x = src[idx * 3 + 0], y = src[idx * 3 + 1], z = src[idx * 3 + 2];
    float w = -0.5f * (x * x + y * y + z * z);
    pk[j] = make_float4(x, y, z, w);
    int  slot = j & 1;
    long base = (long)(j >> 1) * 8;
    prf[base + 0 + slot] = x;
    prf[base + 2 + slot] = y;
    prf[base + 4 + slot] = z;
    prf[base + 6 + slot] = w;
}

__global__ __launch_bounds__(512, 8) void chamfer_pk(
        const float4* __restrict__ pk, const float4* __restrict__ pr,
        float* __restrict__ seg) {
    __shared__ float red[8][256];
    int tid  = threadIdx.x;
    int wv   = __builtin_amdgcn_readfirstlane(tid >> 6);
    int lane = tid & 63;
    int bx   = blockIdx.x;
    int tile = bx & 31;
    int b    = (bx >> 5) & 3;
    int dir  = (bx >> 7) & 1;
    int mq   = bx >> 8;

    const float4* __restrict__ A = pk + ((size_t)dir * BATCH + b) * NPTS;
    int n_base = tile * 256;
    v2f px[4], py[4], pz[4], e2[4];
#pragma unroll
    for (int r = 0; r < 4; ++r) {
        float4 p = A[n_base + lane + 64 * r];
        px[r] = (v2f){p.x, p.x};
        py[r] = (v2f){p.y, p.y};
        pz[r] = (v2f){p.z, p.z};
        e2[r] = (v2f){-1e30f, -1e30f};
    }
    int sb_m = (1 - dir) * BATCH + b;
    const float4* __restrict__ mp =
        pr + ((size_t)sb_m * 4096 + mq * 1024 + wv * 128) * 2;

    for (int i = 0; i < 128; i += 4) {
#pragma unroll
        for (int u = 0; u < 4; ++u) {
            float4 qa = mp[(i + u) * 2 + 0];
            float4 qb = mp[(i + u) * 2 + 1];
            v2f qx = (v2f){qa.x, qa.y};
            v2f qy = (v2f){qa.z, qa.w};
            v2f qz = (v2f){qb.x, qb.y};
            v2f qw = (v2f){qb.z, qb.w};
#pragma unroll
            for (int r = 0; r < 4; ++r) {
                v2f c = __builtin_elementwise_fma(px[r], qx, qw);
                c = __builtin_elementwise_fma(py[r], qy, c);
                c = __builtin_elementwise_fma(pz[r], qz, c);
                e2[r] = __builtin_elementwise_max(e2[r], c);
            }
        }
    }
#pragma unroll
    for (int r = 0; r < 4; ++r)
        red[wv][lane + 64 * r] = fmaxf(e2[r].x, e2[r].y);
    __syncthreads();
    if (tid < 256) {
        float emax = red[0][tid];
#pragma unroll
        for (int ww = 1; ww < 8; ++ww) emax = fmaxf(emax, red[ww][tid]);
        seg[mq * (2 * BATCH * NPTS) + dir * (BATCH * NPTS) + b * NPTS
            + n_base + tid] = emax;
    }
}

__global__ __launch_bounds__(1024) void finalize_pk(
        const float4* __restrict__ pk, const float* __restrict__ seg,
        float* __restrict__ out) {
    __shared__ float partial[16];
    int j = blockIdx.x * 1024 + threadIdx.x;
    float emax = seg[j];
#pragma unroll
    for (int q = 1; q < 4; ++q) emax = fmaxf(emax, seg[q * 65536 + j]);
    float dist = fmaxf(-2.0f * (emax + pk[j].w), 0.0f);
    for (int off = 32; off > 0; off >>= 1)
        dist += __shfl_down(dist, off, 64);
    int lane = threadIdx.x & 63, wv = threadIdx.x >> 6;
    if (lane == 0) partial[wv] = dist;
    __syncthreads();
    if (threadIdx.x < 16) {
        float s = partial[threadIdx.x];
        for (int off = 8; off > 0; off >>= 1)
            s += __shfl_down(s, off, 64);
        if (threadIdx.x == 0) atomicAdd(out, s * (1.0f / 32768.0f));
    }
}

// ============================================================================
// Fallback 2 (no ws): verified R2 kernel.
// ============================================================================

__global__ void zero_out_kernel(float* __restrict__ out) { out[0] = 0.0f; }

__global__ __launch_bounds__(1024) void chamfer_fallback(
        const float* __restrict__ f, const float* __restrict__ f_,
        float* __restrict__ out) {
    __shared__ float wlds[NPTS];
    __shared__ float red[16][256];
    __shared__ float partial[4];
    int tid  = threadIdx.x;
    int wv   = __builtin_amdgcn_readfirstlane(tid >> 6);
    int lane = tid & 63;
    int bx   = blockIdx.x;
    int dir  = bx >> 7;
    int b    = (bx >> 5) & 3;
    int tile = bx & 31;
    int n_base = tile * 256;
    const float* __restrict__ A  = dir ? f_ : f;
    const float* __restrict__ Bm = dir ? f  : f_;
    const float* an = A  + (size_t)b * NPTS * 3;
    const float* bm = Bm + (size_t)b * NPTS * 3;
    for (int i = tid; i < NPTS; i += 1024) {
        float x = bm[i * 3 + 0], y = bm[i * 3 + 1], z = bm[i * 3 + 2];
        wlds[i] = -0.5f * (x * x + y * y + z * z);
    }
    float xn[4], yn[4], zn[4];
#pragma unroll
    for (int r = 0; r < 4; ++r) {
        int n = n_base + lane + 64 * r;
        xn[r] = an[n * 3 + 0]; yn[r] = an[n * 3 + 1]; zn[r] = an[n * 3 + 2];
    }
    __syncthreads();
    float e[4];
#pragma unroll
    for (int r = 0; r < 4; ++r) e[r] = -1e30f;
    int m0 = wv * (NPTS / 16);
#pragma unroll 4
    for (int i = 0; i < NPTS / 16; ++i) {
        int m = m0 + i;
        float qx = bm[m * 3 + 0], qy = bm[m * 3 + 1], qz = bm[m * 3 + 2];
        float qw = wlds[m];
#pragma unroll
        for (int r = 0; r < 4; ++r) {
            float c = fmaf(zn[r], qz, fmaf(yn[r], qy, fmaf(xn[r], qx, qw)));
            e[r] = fmaxf(e[r], c);
        }
    }
#pragma unroll
    for (int r = 0; r < 4; ++r) red[wv][lane + 64 * r] = e[r];
    __syncthreads();
    if (tid < 256) {
        float emax = red[0][tid];
#pragma unroll
        for (int ww = 1; ww < 16; ++ww) emax = fmaxf(emax, red[ww][tid]);
        int n = n_base + tid;
        float x = an[n * 3 + 0], y = an[n * 3 + 1], z = an[n * 3 + 2];
        float dist = fmaxf(x * x + y * y + z * z - 2.0f * emax, 0.0f);
        for (int off = 32; off > 0; off >>= 1)
            dist += __shfl_down(dist, off, 64);
        if ((tid & 63) == 0) partial[tid >> 6] = dist;
    }
    __syncthreads();
    if (tid == 0) {
        float s = partial[0] + partial[1] + partial[2] + partial[3];
        atomicAdd(out, s * (1.0f / 32768.0f));
    }
}

extern "C" void kernel_launch(void* const* d_in, const int* in_sizes, int n_in,
                              void* d_out, int out_size, void* d_ws, size_t ws_size,
                              hipStream_t stream) {
    const float* f  = (const float*)d_in[0];
    const float* f_ = (const float*)d_in[1];
    float* out = (float*)d_out;

    const size_t MB = 1048576;
    if (ws_size >= 5 * MB) {
        bf8*      fA  = (bf8*)d_ws;                        // f  as A-role, 1 MB
        bf8*      fB  = (bf8*)((char*)d_ws + 1 * MB);      // f  as B-role
        bf8*      gA  = (bf8*)((char*)d_ws + 2 * MB);      // f_ as A-role
        bf8*      gB  = (bf8*)((char*)d_ws + 3 * MB);      // f_ as B-role
        unsigned* seg = (unsigned*)((char*)d_ws + 4 * MB); // 256 KB
        pack_mfma<<<256, 256, 0, stream>>>(f, f_, fA, fB, gA, gB, seg, out);
        chamfer_mfma<<<512, 512, 0, stream>>>(fA, fB, gA, gB, seg);
        finalize_mfma<<<64, 1024, 0, stream>>>(seg, out);
    } else if (ws_size >= 3 * MB) {
        float4* pk = (float4*)d_ws;
        float4* pr = (float4*)((char*)d_ws + 1 * MB);
        float*  sg = (float*)((char*)d_ws + 2 * MB);
        pack_pk<<<256, 256, 0, stream>>>(f, f_, pk, (float*)pr, out);
        chamfer_pk<<<1024, 512, 0, stream>>>(pk, pr, sg);
        finalize_pk<<<64, 1024, 0, stream>>>(pk, sg, out);
    } else {
        zero_out_kernel<<<1, 1, 0, stream>>>(out);
        chamfer_fallback<<<256, 1024, 0, stream>>>(f, f_, out);
    }
}